// Round 15
// baseline (624.119 us; speedup 1.0000x reference)
//
#include <hip/hip_runtime.h>
#include <math.h>

namespace {

constexpr int NL = 4;      // layers
constexpr int DM = 256;    // d_model
constexpr int DI = 512;    // d_inner
constexpr int DS = 16;     // d_state
constexpr int DR = 16;     // dt_rank
constexpr int NF = 32;     // n_features
constexpr int NB = 8;      // batch
constexpr int T  = 2048;   // seq
constexpr int ROWS = NB * T;       // 16384
constexpr int XD = DR + 2 * DS;    // 48
constexpr int NC = 64;             // scan chunks
constexpr int CL = T / NC;         // 32 steps per chunk
constexpr int SCN = NB * DI * DS;  // 65536 scan states

constexpr float LOG2E = 1.44269504088896341f;
constexpr float LN2   = 0.69314718055994531f;

typedef __attribute__((ext_vector_type(4))) float f32x4;
typedef __attribute__((ext_vector_type(8))) short bf16x8;

__device__ __forceinline__ float fexp2(float x) { return __builtin_amdgcn_exp2f(x); }
__device__ __forceinline__ float frcp(float x)  { return __builtin_amdgcn_rcpf(x); }
__device__ __forceinline__ float flog2(float x) { return __builtin_amdgcn_logf(x); }

__device__ __forceinline__ float siluf(float x) {
    return x * frcp(1.f + fexp2(-LOG2E * x));
}
__device__ __forceinline__ float softplusf(float x) {
    return fmaxf(x, 0.f) + LN2 * flog2(1.f + fexp2(-LOG2E * fabsf(x)));
}
__device__ __forceinline__ short f2bf(float f) {   // RNE float->bf16
    union { float f; unsigned u; } c; c.f = f;
    unsigned r = (c.u + 0x7FFFu + ((c.u >> 16) & 1u)) >> 16;
    return (short)r;
}
__device__ __forceinline__ float bf2f(short s) {
    union { unsigned u; float f; } c; c.u = ((unsigned)(unsigned short)s) << 16;
    return c.f;
}
// a[s] = g^(s+1), s=0..15, depth-4 multiply tree
__device__ __forceinline__ void powers16(float g, float* a) {
    float g2 = g * g, g4 = g2 * g2, g8 = g4 * g4;
    a[0] = g;        a[1] = g2;       a[2] = g * g2;   a[3] = g4;
    a[4] = g * g4;   a[5] = g2 * g4;  a[6] = a[2] * g4; a[7] = g8;
    a[8] = g * g8;   a[9] = g2 * g8;  a[10] = a[2] * g8; a[11] = g4 * g8;
    a[12] = a[4] * g8; a[13] = a[5] * g8; a[14] = a[6] * g8; a[15] = g8 * g8;
}

// ---------------------------------------------------------------------------
// All prep in ONE kernel.  inWt has ln_w folded; colsum/bb carry the LN
// mean/bias terms; stats buffer zeroed.
// ---------------------------------------------------------------------------
constexpr int PN1 = NL * 1024 * DM;   // inWt (ln_w-folded)
constexpr int PN2 = NL * 64 * DI;     // xpWt
constexpr int PN3 = NL * DM * DI;     // outWt
constexpr int PN4 = DM * NF;          // inwT
constexpr int PN5 = NL * DI * DR;     // dtWt
constexpr int PN6 = NL * DI * DS;     // negA2
constexpr int PN7 = ROWS * NF;        // xb
constexpr int PN8 = NL * 1024 * 2;    // colsum | bb
constexpr int PN9 = ROWS * 2;         // stats zero
constexpr int PTOT = PN1 + PN2 + PN3 + PN4 + PN5 + PN6 + PN7 + PN8 + PN9;

__global__ void prep_all(const float* __restrict__ inW, const float* __restrict__ xpW,
                         const float* __restrict__ outW, const float* __restrict__ in_w,
                         const float* __restrict__ dtW, const float* __restrict__ A_log,
                         const float* __restrict__ x, const float* __restrict__ ln_w,
                         const float* __restrict__ ln_b,
                         short* __restrict__ inWt, short* __restrict__ xpWt,
                         short* __restrict__ outWt, short* __restrict__ inwT,
                         float* __restrict__ dtWt, float* __restrict__ negA2,
                         short* __restrict__ xb, float* __restrict__ colsum,
                         float* __restrict__ bb, float* __restrict__ stats)
{
    int idx = blockIdx.x * 256 + threadIdx.x;
    if (idx < PN1) {                       // inWt[l][n][k] = ln_w[l][k]*inW[l][k][n]
        int l = idx / (1024 * DM), r = idx - l * (1024 * DM);
        int n = r / DM, k = r - n * DM;
        inWt[idx] = f2bf(ln_w[l * DM + k] * inW[(size_t)l * DM * 1024 + (size_t)k * 1024 + n]);
        return;
    }
    idx -= PN1;
    if (idx < PN2) {                       // xpWt[l][n(64)][k(DI)], pad n>=XD
        int l = idx / (64 * DI), r = idx - l * (64 * DI);
        int n = r / DI, k = r - n * DI;
        xpWt[idx] = (n < XD) ? f2bf(xpW[(size_t)l * DI * XD + (size_t)k * XD + n]) : (short)0;
        return;
    }
    idx -= PN2;
    if (idx < PN3) {                       // outWt[l][n(DM)][k(DI)]
        int l = idx / (DM * DI), r = idx - l * (DM * DI);
        int n = r / DI, k = r - n * DI;
        outWt[idx] = f2bf(outW[(size_t)l * DI * DM + (size_t)k * DM + n]);
        return;
    }
    idx -= PN3;
    if (idx < PN4) {                       // inwT[n(DM)][k(NF)]
        int n = idx / NF, k = idx - n * NF;
        inwT[idx] = f2bf(in_w[(size_t)k * DM + n]);
        return;
    }
    idx -= PN4;
    if (idx < PN5) {                       // dtWt[l][d][r] = dtW[l][r][d]
        int l = idx / (DI * DR), r0 = idx - l * (DI * DR);
        int d = r0 / DR, rr = r0 - d * DR;
        dtWt[idx] = dtW[(size_t)l * DR * DI + (size_t)rr * DI + d];
        return;
    }
    idx -= PN5;
    if (idx < PN6) {                       // negA2 = -log2e*exp(A_log)
        negA2[idx] = -LOG2E * fexp2(LOG2E * A_log[idx]);
        return;
    }
    idx -= PN6;
    if (idx < PN7) { xb[idx] = f2bf(x[idx]); return; }
    idx -= PN7;
    if (idx < PN8) {                       // colsum[l][n] / bb[l][n]
        int l = idx / 2048, r = idx - l * 2048;
        int which = r >> 10, n = r & 1023;
        const float* wv = which ? (ln_b + l * DM) : (ln_w + l * DM);
        float s = 0.f;
        for (int k = 0; k < DM; ++k)
            s += wv[k] * inW[(size_t)l * DM * 1024 + (size_t)k * 1024 + n];
        (which ? bb : colsum)[l * 1024 + n] = s;
        return;
    }
    idx -= PN8;
    if (idx < PN9) stats[idx] = 0.f;
}

// ---------------------------------------------------------------------------
// MFMA bf16 GEMM.  A[M,K] bf16, Bt[Npad][K] bf16.  Tile BMxBN, 4 waves (2x2).
// XCD-aware 1-D swizzle.
// EP 0: LN-fused in-proj: v = rs*acc - rs*mu*colsum[col] + bb[col];
//       col<512 -> bf16 Cs0 = v; else bf16 Cs1 = silu(v).  Reads stats.
// EP 1: fp32 C[row*ldc+col] = acc for col < Ncut                 [x-proj]
// EP 2: h += acc; write C fp32 + hb bf16; accumulate row stats   [out-proj]
// EP 3: h = acc + bias; write C fp32 + hb bf16; row stats        [first]
// ---------------------------------------------------------------------------
template <int EP, int BM, int BN>
__global__ void gemm_mfma(const short* __restrict__ A, const short* __restrict__ Bt,
                          float* __restrict__ C, short* __restrict__ Cs0,
                          short* __restrict__ Cs1, const float* __restrict__ bias,
                          float* __restrict__ stats, const float* __restrict__ colsum,
                          const float* __restrict__ bb, short* __restrict__ hbw,
                          int K, int lda, int ldc, int Ncut, int NXB, int NYB)
{
    constexpr int MF  = BM / 32;          // m-frags per wave
    constexpr int NFr = BN / 32;          // n-frags per wave
    __shared__ short smem[BM * 40 + BN * 40];
    const int bid = blockIdx.x;
    const int xcd = bid & 7, j = bid >> 3;
    const int by = xcd * (NYB >> 3) + j / NXB;
    const int bx = j - (j / NXB) * NXB;
    const int m0 = by * BM;
    const int n0 = bx * BN;

    const int tid = threadIdx.x;
    const int lane = tid & 63, w = tid >> 6;
    const int wr = w >> 1, wc = w & 1;
    const int lr = lane & 15, lk = lane >> 4;

    f32x4 acc[MF][NFr] = {};
    for (int k0 = 0; k0 < K; k0 += 32) {
        __syncthreads();
#pragma unroll
        for (int i = 0; i < BM / 64; ++i) {
            int c = tid + i * 256;
            int row = c >> 2, seg = c & 3;
            bf16x8 v = *(const bf16x8*)(A + (size_t)(m0 + row) * lda + k0 + seg * 8);
            *(bf16x8*)(&smem[row * 40 + seg * 8]) = v;
        }
#pragma unroll
        for (int i = 0; i < BN / 64; ++i) {
            int c = tid + i * 256;
            int row = c >> 2, seg = c & 3;
            bf16x8 v = *(const bf16x8*)(Bt + (size_t)(n0 + row) * K + k0 + seg * 8);
            *(bf16x8*)(&smem[BM * 40 + row * 40 + seg * 8]) = v;
        }
        __syncthreads();
        bf16x8 af[MF], bfr[NFr];
#pragma unroll
        for (int m = 0; m < MF; ++m)
            af[m] = *(const bf16x8*)(&smem[(wr * (BM / 2) + m * 16 + lr) * 40 + lk * 8]);
#pragma unroll
        for (int n = 0; n < NFr; ++n)
            bfr[n] = *(const bf16x8*)(&smem[BM * 40 + (wc * (BN / 2) + n * 16 + lr) * 40 + lk * 8]);
#pragma unroll
        for (int m = 0; m < MF; ++m)
#pragma unroll
            for (int n = 0; n < NFr; ++n)
                acc[m][n] = __builtin_amdgcn_mfma_f32_16x16x32_bf16(af[m], bfr[n], acc[m][n], 0, 0, 0);
    }
#pragma unroll
    for (int m = 0; m < MF; ++m) {
#pragma unroll
        for (int j2 = 0; j2 < 4; ++j2) {
            const int row = m0 + wr * (BM / 2) + m * 16 + lk * 4 + j2;
            float mu = 0.f, rsv = 0.f;
            if (EP == 0) {
                float s1 = stats[row * 2], s2 = stats[row * 2 + 1];
                mu = s1 * (1.f / DM);
                float var = s2 * (1.f / DM) - mu * mu;
                rsv = 1.f / sqrtf(var + 1e-5f);
            }
            float s1 = 0.f, s2 = 0.f;
#pragma unroll
            for (int n = 0; n < NFr; ++n) {
                const int col = n0 + wc * (BN / 2) + n * 16 + lr;
                float v = acc[m][n][j2];
                if (EP == 0) {
                    v = rsv * v - rsv * mu * colsum[col] + bb[col];
                    if (col < DI) Cs0[(size_t)row * DI + col] = f2bf(v);
                    else          Cs1[(size_t)row * DI + col - DI] = f2bf(siluf(v));
                } else if (EP == 1) {
                    if (col < Ncut) C[(size_t)row * ldc + col] = v;
                } else {
                    if (EP == 2) v += C[(size_t)row * ldc + col];
                    else         v += bias[col];
                    C[(size_t)row * ldc + col] = v;
                    hbw[(size_t)row * ldc + col] = f2bf(v);
                    s1 += v; s2 += v * v;
                }
            }
            if (EP == 2 || EP == 3) {
                s1 += __shfl_xor(s1, 1); s2 += __shfl_xor(s2, 1);
                s1 += __shfl_xor(s1, 2); s2 += __shfl_xor(s2, 2);
                s1 += __shfl_xor(s1, 4); s2 += __shfl_xor(s2, 4);
                s1 += __shfl_xor(s1, 8); s2 += __shfl_xor(s2, 8);
                if (lr == 0) {
                    atomicAdd(&stats[row * 2], s1);
                    atomicAdd(&stats[row * 2 + 1], s2);
                }
            }
        }
    }
}

// ---------------------------------------------------------------------------
// Depthwise causal conv (width 4) + bias + SiLU.  bf16 in/out, 8 chans/thread.
// ---------------------------------------------------------------------------
__global__ void conv_silu_kernel(const short* __restrict__ xsb,
                                 const float* __restrict__ W,   // [4, DI]
                                 const float* __restrict__ Bc,  // [DI]
                                 short* __restrict__ xcb)
{
    const int idx = blockIdx.x * 256 + threadIdx.x;   // over ROWS*DI/8
    const int c8 = idx & (DI / 8 - 1);
    const int bt = idx >> 6;
    const int t = bt & (T - 1);
    const int c = c8 * 8;
    float acc[8];
    f32x4 b0 = *(const f32x4*)(Bc + c);
    f32x4 b1 = *(const f32x4*)(Bc + c + 4);
#pragma unroll
    for (int q = 0; q < 4; ++q) { acc[q] = b0[q]; acc[q + 4] = b1[q]; }
#pragma unroll
    for (int k = 0; k < 4; ++k) {
        int tt = t + k - 3;
        if (tt >= 0) {
            bf16x8 v = *(const bf16x8*)(xsb + (size_t)(bt + k - 3) * DI + c);
            f32x4 w0 = *(const f32x4*)(W + k * DI + c);
            f32x4 w1 = *(const f32x4*)(W + k * DI + c + 4);
#pragma unroll
            for (int q = 0; q < 4; ++q) {
                acc[q]     += bf2f(v[q]) * w0[q];
                acc[q + 4] += bf2f(v[q + 4]) * w1[q];
            }
        }
    }
    bf16x8 o;
#pragma unroll
    for (int q = 0; q < 8; ++q) o[q] = f2bf(siluf(acc[q]));
    *(bf16x8*)(xcb + (size_t)idx * 8) = o;
}

// ---------------------------------------------------------------------------
// Chunked selective scan, lane-per-d; dt-projection fused; structured-A
// fast path (a[s] = g^(s+1)) with generic 16-exp fallback.
// xd values are wave-uniform -> read through uniform (scalar) loads; no LDS.
// ---------------------------------------------------------------------------
__global__ void scan_pass1(const float* __restrict__ xd,
                           const short* __restrict__ xcb,
                           const float* __restrict__ negA2, // [DI*DS] slice
                           const float* __restrict__ dtWt,  // [DI*DR] slice
                           const float* __restrict__ dtB,   // [DI] slice
                           float* __restrict__ S, float* __restrict__ sdtb)
{
    const int d = blockIdx.x * 256 + threadIdx.x;
    const int c = blockIdx.y;
    const int b = blockIdx.z;
    const int row0 = b * T + c * CL;

    float A2[DS], h[DS], wcol[DR];
#pragma unroll
    for (int q = 0; q < 4; ++q) {
        *(f32x4*)&A2[q * 4]   = *(const f32x4*)(negA2 + d * DS + q * 4);
        *(f32x4*)&wcol[q * 4] = *(const f32x4*)(dtWt + d * DR + q * 4);
    }
    bool fastb = true;
#pragma unroll
    for (int s = 1; s < DS; ++s)
        fastb = fastb && (fabsf(A2[s] - A2[0] * (float)(s + 1)) <= 1e-4f * fabsf(A2[s]));
    const bool fast = __all(fastb);
#pragma unroll
    for (int s = 0; s < DS; ++s) h[s] = 0.f;
    const float dtBd = dtB[d];
    float sdt = 0.f;

    for (int t = 0; t < CL; ++t) {
        const float* __restrict__ xr = xd + (size_t)(row0 + t) * XD;  // uniform
        float xcv = bf2f(xcb[(size_t)(row0 + t) * DI + d]);
        float accd = dtBd;
#pragma unroll
        for (int r = 0; r < DR; ++r) accd += xr[r] * wcol[r];
        float dtv = softplusf(accd);
        float dx = dtv * xcv;
        sdt += dtv;
        float a[DS];
        if (fast) powers16(fexp2(dtv * A2[0]), a);
        else {
#pragma unroll
            for (int s = 0; s < DS; ++s) a[s] = fexp2(dtv * A2[s]);
        }
#pragma unroll
        for (int s = 0; s < DS; ++s)
            h[s] = a[s] * h[s] + dx * xr[DR + s];
    }
    const size_t base = (size_t)c * SCN + ((size_t)b * DI + d) * DS;
#pragma unroll
    for (int q = 0; q < 4; ++q)
        *(f32x4*)(S + base + q * 4) = *(f32x4*)&h[q * 4];
    sdtb[c * (NB * DI) + b * DI + d] = sdt;
}

// In-place combine: S[c] <- state entering chunk c (recomputes decay from sdt).
__global__ void scan_combine(float* __restrict__ S, const float* __restrict__ sdtb,
                             const float* __restrict__ negA2)
{
    const int idx3 = blockIdx.x * blockDim.x + threadIdx.x;  // SCN
    const int bd = idx3 >> 4;
    const float A2c = negA2[(bd & (DI - 1)) * DS + (idx3 & 15)];
    float h = 0.f;
    for (int c = 0; c < NC; ++c) {
        float sc = S[(size_t)c * SCN + idx3];
        float pc = fexp2(A2c * sdtb[c * (NB * DI) + bd]);
        S[(size_t)c * SCN + idx3] = h;
        h = pc * h + sc;
    }
}

__global__ void scan_pass2(const float* __restrict__ xd,
                           const short* __restrict__ xcb,
                           const float* __restrict__ negA2,
                           const float* __restrict__ dtWt,
                           const float* __restrict__ dtB,
                           const float* __restrict__ Dv,
                           const float* __restrict__ H,    // [NC][SCN] (=S)
                           const short* __restrict__ zgb,  // bf16 silu(z)
                           short* __restrict__ yb,         // bf16 out (gated)
                           float* __restrict__ stats)      // zeroed for out-proj
{
    const int d = blockIdx.x * 256 + threadIdx.x;
    const int c = blockIdx.y;
    const int b = blockIdx.z;
    const int row0 = b * T + c * CL;

    // zero the row-stats slots this (c,b) tile owns (for the following out-proj)
    if (blockIdx.x == 0 && threadIdx.x < CL * 2)
        stats[(size_t)(row0 + (threadIdx.x >> 1)) * 2 + (threadIdx.x & 1)] = 0.f;

    float A2[DS], h[DS], wcol[DR];
#pragma unroll
    for (int q = 0; q < 4; ++q) {
        *(f32x4*)&A2[q * 4]   = *(const f32x4*)(negA2 + d * DS + q * 4);
        *(f32x4*)&wcol[q * 4] = *(const f32x4*)(dtWt + d * DR + q * 4);
    }
    bool fastb = true;
#pragma unroll
    for (int s = 1; s < DS; ++s)
        fastb = fastb && (fabsf(A2[s] - A2[0] * (float)(s + 1)) <= 1e-4f * fabsf(A2[s]));
    const bool fast = __all(fastb);
    const size_t base = (size_t)c * SCN + ((size_t)b * DI + d) * DS;
#pragma unroll
    for (int q = 0; q < 4; ++q)
        *(f32x4*)&h[q * 4] = *(const f32x4*)(H + base + q * 4);
    const float dtBd = dtB[d];
    const float Dd = Dv[d];

    for (int t = 0; t < CL; ++t) {
        const size_t row = (size_t)(row0 + t);
        const float* __restrict__ xr = xd + row * XD;   // uniform
        float xcv = bf2f(xcb[row * DI + d]);
        float zg  = bf2f(zgb[row * DI + d]);
        float accd = dtBd;
#pragma unroll
        for (int r = 0; r < DR; ++r) accd += xr[r] * wcol[r];
        float dtv = softplusf(accd);
        float dx = dtv * xcv;
        float a[DS];
        if (fast) powers16(fexp2(dtv * A2[0]), a);
        else {
#pragma unroll
            for (int s = 0; s < DS; ++s) a[s] = fexp2(dtv * A2[s]);
        }
        float acc0 = 0.f, acc1 = 0.f, acc2 = 0.f, acc3 = 0.f;
#pragma unroll
        for (int q = 0; q < 4; ++q) {
            h[q * 4 + 0] = a[q * 4 + 0] * h[q * 4 + 0] + dx * xr[DR + q * 4 + 0];
            acc0 += h[q * 4 + 0] * xr[DR + DS + q * 4 + 0];
            h[q * 4 + 1] = a[q * 4 + 1] * h[q * 4 + 1] + dx * xr[DR + q * 4 + 1];
            acc1 += h[q * 4 + 1] * xr[DR + DS + q * 4 + 1];
            h[q * 4 + 2] = a[q * 4 + 2] * h[q * 4 + 2] + dx * xr[DR + q * 4 + 2];
            acc2 += h[q * 4 + 2] * xr[DR + DS + q * 4 + 2];
            h[q * 4 + 3] = a[q * 4 + 3] * h[q * 4 + 3] + dx * xr[DR + q * 4 + 3];
            acc3 += h[q * 4 + 3] * xr[DR + DS + q * 4 + 3];
        }
        float yv = (acc0 + acc1) + (acc2 + acc3);
        yb[row * DI + d] = f2bf((yv + xcv * Dd) * zg);
    }
}

// ---------------------------------------------------------------------------
// Head: final LN on last token, gelu(last@h1W+h1b) @ h2W + h2b.
// ---------------------------------------------------------------------------
__global__ void head_kernel(const float* __restrict__ h,
                            const float* __restrict__ fw, const float* __restrict__ fb,
                            const float* __restrict__ h1W, const float* __restrict__ h1b,
                            const float* __restrict__ h2W, const float* __restrict__ h2b,
                            float* __restrict__ out)
{
    const int bi = blockIdx.x;
    const int t = threadIdx.x;
    const int wid = t >> 6, lane = t & 63;
    __shared__ float red[4];
    __shared__ float ln[DM];
    __shared__ float hid[DM / 2];

    const float* row = h + ((bi + 1) * T - 1) * DM;
    float v = row[t];
    float s = v;
#pragma unroll
    for (int o = 32; o >= 1; o >>= 1) s += __shfl_xor(s, o);
    if (lane == 0) red[wid] = s;
    __syncthreads();
    float mu = (red[0] + red[1] + red[2] + red[3]) * (1.f / DM);
    __syncthreads();
    float d = v - mu;
    float q = d * d;
#pragma unroll
    for (int o = 32; o >= 1; o >>= 1) q += __shfl_xor(q, o);
    if (lane == 0) red[wid] = q;
    __syncthreads();
    float var = (red[0] + red[1] + red[2] + red[3]) * (1.f / DM);
    ln[t] = d * (1.f / sqrtf(var + 1e-5f)) * fw[t] + fb[t];
    __syncthreads();

    if (t < DM / 2) {
        float acc = h1b[t];
        for (int k = 0; k < DM; ++k) acc += ln[k] * h1W[k * (DM / 2) + t];
        float x3 = acc * acc * acc;
        hid[t] = 0.5f * acc * (1.f + tanhf(0.7978845608028654f * (acc + 0.044715f * x3)));
    }
    __syncthreads();
    if (t < 3) {
        float acc = h2b[t];
        for (int k = 0; k < DM / 2; ++k) acc += hid[k] * h2W[k * 3 + t];
        out[bi * 3 + t] = acc;
    }
}

} // namespace

extern "C" void kernel_launch(void* const* d_in, const int* in_sizes, int n_in,
                              void* d_out, int out_size, void* d_ws, size_t ws_size,
                              hipStream_t stream)
{
    (void)in_sizes; (void)n_in; (void)out_size; (void)ws_size;
    const float* x     = (const float*)d_in[0];
    const float* in_w  = (const float*)d_in[1];
    const float* in_b  = (const float*)d_in[2];
    const float* ln_w  = (const float*)d_in[3];
    const float* ln_b  = (const float*)d_in[4];
    const float* inW   = (const float*)d_in[5];
    const float* convW = (const float*)d_in[6];
    const float* convB = (const float*)d_in[7];
    const float* xpW   = (const float*)d_in[8];
    const float* dtW   = (const float*)d_in[9];
    const float* A_log = (const float*)d_in[10];
    const float* Dv    = (const float*)d_in[11];
    const float* outW  = (const float*)d_in[12];
    const float* fln_w = (const float*)d_in[13];
    const float* fln_b = (const float*)d_in[14];
    const float* h1W   = (const float*)d_in[15];
    const float* h1b   = (const float*)d_in[16];
    const float* h2W   = (const float*)d_in[17];
    const float* h2b   = (const float*)d_in[18];
    const float* dtB   = (const float*)d_in[19];
    float* out = (float*)d_out;

    float* w = (float*)d_ws;
    float* hbuf   = w;  w += ROWS * DM;
    float* xd     = w;  w += ROWS * XD;
    float* S      = w;  w += (size_t)SCN * NC;
    float* sdtb   = w;  w += NC * NB * DI;
    float* negA2  = w;  w += NL * DI * DS;
    float* dtWt   = w;  w += NL * DI * DR;
    float* colsum = w;  w += NL * 1024;
    float* bbv    = w;  w += NL * 1024;
    float* stats  = w;  w += ROWS * 2;
    short* hb    = (short*)w;
    short* xb    = hb   + (size_t)ROWS * DM;
    short* xsb   = xb   + (size_t)ROWS * NF;
    short* zgb   = xsb  + (size_t)ROWS * DI;
    short* xcb   = zgb  + (size_t)ROWS * DI;
    short* yb    = xcb  + (size_t)ROWS * DI;
    short* inWt  = yb   + (size_t)ROWS * DI;      // [4][1024][256] (ln_w-folded)
    short* xpWt  = inWt + (size_t)NL * 1024 * DM; // [4][64][512]
    short* outWt = xpWt + (size_t)NL * 64 * DI;   // [4][256][512]
    short* inwT  = outWt + (size_t)NL * DM * DI;  // [256][32]

    // --- all prep in one launch ---
    prep_all<<<(PTOT + 255) / 256, 256, 0, stream>>>(
        inW, xpW, outW, in_w, dtW, A_log, x, ln_w, ln_b,
        inWt, xpWt, outWt, inwT, dtWt, negA2, xb, colsum, bbv, stats);

    // h = x @ in_w + in_b  (MFMA; writes hbuf fp32 + hb bf16 + row stats)
    gemm_mfma<3, 128, 64><<<(DM / 64) * (ROWS / 128), 256, 0, stream>>>(
        xb, inwT, hbuf, nullptr, nullptr, in_b, stats, nullptr, nullptr, hb,
        NF, NF, DM, 0, DM / 64, ROWS / 128);

    for (int i = 0; i < NL; ++i) {
        // LN-fused in-proj: xz = LN(h) @ inW[i] -> bf16 xs | bf16 silu(z)
        gemm_mfma<0, 128, 128><<<(1024 / 128) * (ROWS / 128), 256, 0, stream>>>(
            hb, inWt + (size_t)i * 1024 * DM, nullptr, xsb, zgb, nullptr,
            stats, colsum + i * 1024, bbv + i * 1024, nullptr,
            DM, DM, 0, 0, 1024 / 128, ROWS / 128);

        conv_silu_kernel<<<ROWS * DI / 2048, 256, 0, stream>>>(
            xsb, convW + i * 4 * DI, convB + i * DI, xcb);

        // xd = xc @ xpW[i]   (BM=64 tile -> 256 blocks)
        gemm_mfma<1, 64, 64><<<1 * (ROWS / 64), 256, 0, stream>>>(
            xcb, xpWt + (size_t)i * 64 * DI, xd, nullptr, nullptr, nullptr,
            nullptr, nullptr, nullptr, nullptr, DI, DI, XD, XD, 1, ROWS / 64);

        scan_pass1<<<dim3(DI / 256, NC, NB), 256, 0, stream>>>(
            xd, xcb, negA2 + i * DI * DS, dtWt + i * DI * DR, dtB + i * DI, S, sdtb);
        scan_combine<<<SCN / 256, 256, 0, stream>>>(S, sdtb, negA2 + i * DI * DS);
        scan_pass2<<<dim3(DI / 256, NC, NB), 256, 0, stream>>>(
            xd, xcb, negA2 + i * DI * DS, dtWt + i * DI * DR, dtB + i * DI,
            Dv + i * DI, S, zgb, yb, stats);

        // h += y @ outW[i]; writes hbuf fp32 + hb bf16 + row stats
        gemm_mfma<2, 128, 128><<<(DM / 128) * (ROWS / 128), 256, 0, stream>>>(
            yb, outWt + (size_t)i * DM * DI, hbuf, nullptr, nullptr, nullptr,
            stats, nullptr, nullptr, hb, DI, DI, DM, 0, DM / 128, ROWS / 128);
    }

    head_kernel<<<NB, DM, 0, stream>>>(hbuf, fln_w, fln_b, h1W, h1b, h2W, h2b, out);
}

// Round 16
// 592.289 us; speedup vs baseline: 1.0537x; 1.0537x over previous
//
#include <hip/hip_runtime.h>
#include <math.h>

namespace {

constexpr int NL = 4;      // layers
constexpr int DM = 256;    // d_model
constexpr int DI = 512;    // d_inner
constexpr int DS = 16;     // d_state
constexpr int DR = 16;     // dt_rank
constexpr int NF = 32;     // n_features
constexpr int NB = 8;      // batch
constexpr int T  = 2048;   // seq
constexpr int ROWS = NB * T;       // 16384
constexpr int XD = DR + 2 * DS;    // 48
constexpr int NC = 64;             // scan chunks
constexpr int CL = T / NC;         // 32 steps per chunk
constexpr int SCN = NB * DI * DS;  // 65536 scan states

constexpr float LOG2E = 1.44269504088896341f;
constexpr float LN2   = 0.69314718055994531f;

typedef __attribute__((ext_vector_type(4))) float f32x4;
typedef __attribute__((ext_vector_type(8))) short bf16x8;
typedef __attribute__((ext_vector_type(4))) short s16x4;

__device__ __forceinline__ float fexp2(float x) { return __builtin_amdgcn_exp2f(x); }
__device__ __forceinline__ float frcp(float x)  { return __builtin_amdgcn_rcpf(x); }
__device__ __forceinline__ float flog2(float x) { return __builtin_amdgcn_logf(x); }

__device__ __forceinline__ float siluf(float x) {
    return x * frcp(1.f + fexp2(-LOG2E * x));
}
__device__ __forceinline__ float softplusf(float x) {
    return fmaxf(x, 0.f) + LN2 * flog2(1.f + fexp2(-LOG2E * fabsf(x)));
}
__device__ __forceinline__ short f2bf(float f) {   // RNE float->bf16
    union { float f; unsigned u; } c; c.f = f;
    unsigned r = (c.u + 0x7FFFu + ((c.u >> 16) & 1u)) >> 16;
    return (short)r;
}
__device__ __forceinline__ float bf2f(short s) {
    union { unsigned u; float f; } c; c.u = ((unsigned)(unsigned short)s) << 16;
    return c.f;
}
// a[s] = g^(s+1), s=0..15, depth-4 multiply tree
__device__ __forceinline__ void powers16(float g, float* a) {
    float g2 = g * g, g4 = g2 * g2, g8 = g4 * g4;
    a[0] = g;        a[1] = g2;       a[2] = g * g2;   a[3] = g4;
    a[4] = g * g4;   a[5] = g2 * g4;  a[6] = a[2] * g4; a[7] = g8;
    a[8] = g * g8;   a[9] = g2 * g8;  a[10] = a[2] * g8; a[11] = g4 * g8;
    a[12] = a[4] * g8; a[13] = a[5] * g8; a[14] = a[6] * g8; a[15] = g8 * g8;
}

// ---------------------------------------------------------------------------
// All prep in ONE kernel.  inWt has ln_w folded; colsum/bb carry the LN
// mean/bias terms; stats buffer zeroed.
// ---------------------------------------------------------------------------
constexpr int PN1 = NL * 1024 * DM;   // inWt (ln_w-folded)
constexpr int PN2 = NL * 64 * DI;     // xpWt
constexpr int PN3 = NL * DM * DI;     // outWt
constexpr int PN4 = DM * NF;          // inwT
constexpr int PN5 = NL * DI * DR;     // dtWt
constexpr int PN6 = NL * DI * DS;     // negA2
constexpr int PN7 = ROWS * NF;        // xb
constexpr int PN8 = NL * 1024 * 2;    // colsum | bb
constexpr int PN9 = ROWS * 2;         // stats zero
constexpr int PTOT = PN1 + PN2 + PN3 + PN4 + PN5 + PN6 + PN7 + PN8 + PN9;

__global__ void prep_all(const float* __restrict__ inW, const float* __restrict__ xpW,
                         const float* __restrict__ outW, const float* __restrict__ in_w,
                         const float* __restrict__ dtW, const float* __restrict__ A_log,
                         const float* __restrict__ x, const float* __restrict__ ln_w,
                         const float* __restrict__ ln_b,
                         short* __restrict__ inWt, short* __restrict__ xpWt,
                         short* __restrict__ outWt, short* __restrict__ inwT,
                         float* __restrict__ dtWt, float* __restrict__ negA2,
                         short* __restrict__ xb, float* __restrict__ colsum,
                         float* __restrict__ bb, float* __restrict__ stats)
{
    int idx = blockIdx.x * 256 + threadIdx.x;
    if (idx < PN1) {                       // inWt[l][n][k] = ln_w[l][k]*inW[l][k][n]
        int l = idx / (1024 * DM), r = idx - l * (1024 * DM);
        int n = r / DM, k = r - n * DM;
        inWt[idx] = f2bf(ln_w[l * DM + k] * inW[(size_t)l * DM * 1024 + (size_t)k * 1024 + n]);
        return;
    }
    idx -= PN1;
    if (idx < PN2) {                       // xpWt[l][n(64)][k(DI)], pad n>=XD
        int l = idx / (64 * DI), r = idx - l * (64 * DI);
        int n = r / DI, k = r - n * DI;
        xpWt[idx] = (n < XD) ? f2bf(xpW[(size_t)l * DI * XD + (size_t)k * XD + n]) : (short)0;
        return;
    }
    idx -= PN2;
    if (idx < PN3) {                       // outWt[l][n(DM)][k(DI)]
        int l = idx / (DM * DI), r = idx - l * (DM * DI);
        int n = r / DI, k = r - n * DI;
        outWt[idx] = f2bf(outW[(size_t)l * DI * DM + (size_t)k * DM + n]);
        return;
    }
    idx -= PN3;
    if (idx < PN4) {                       // inwT[n(DM)][k(NF)]
        int n = idx / NF, k = idx - n * NF;
        inwT[idx] = f2bf(in_w[(size_t)k * DM + n]);
        return;
    }
    idx -= PN4;
    if (idx < PN5) {                       // dtWt[l][d][r] = dtW[l][r][d]
        int l = idx / (DI * DR), r0 = idx - l * (DI * DR);
        int d = r0 / DR, rr = r0 - d * DR;
        dtWt[idx] = dtW[(size_t)l * DR * DI + (size_t)rr * DI + d];
        return;
    }
    idx -= PN5;
    if (idx < PN6) {                       // negA2 = -log2e*exp(A_log)
        negA2[idx] = -LOG2E * fexp2(LOG2E * A_log[idx]);
        return;
    }
    idx -= PN6;
    if (idx < PN7) { xb[idx] = f2bf(x[idx]); return; }
    idx -= PN7;
    if (idx < PN8) {                       // colsum[l][n] / bb[l][n]
        int l = idx / 2048, r = idx - l * 2048;
        int which = r >> 10, n = r & 1023;
        const float* wv = which ? (ln_b + l * DM) : (ln_w + l * DM);
        float s = 0.f;
        for (int k = 0; k < DM; ++k)
            s += wv[k] * inW[(size_t)l * DM * 1024 + (size_t)k * 1024 + n];
        (which ? bb : colsum)[l * 1024 + n] = s;
        return;
    }
    idx -= PN8;
    if (idx < PN9) stats[idx] = 0.f;
}

// ---------------------------------------------------------------------------
// MFMA bf16 GEMM.  A[M,K] bf16, Bt[Npad][K] bf16.  Tile BMxBN, 4 waves (2x2).
// XCD-aware 1-D swizzle.
// EP 0: LN-fused in-proj: v = rs*acc - rs*mu*colsum[col] + bb[col];
//       col<512 -> bf16 Cs0 = v; else bf16 Cs1 = silu(v).  Reads stats.
// EP 1: fp32 C[row*ldc+col] = acc for col < Ncut                 [x-proj]
// EP 2: h += acc; write C fp32 + hb bf16; accumulate row stats   [out-proj]
// EP 3: h = acc + bias; write C fp32 + hb bf16; row stats        [first]
// ---------------------------------------------------------------------------
template <int EP, int BM, int BN>
__global__ void gemm_mfma(const short* __restrict__ A, const short* __restrict__ Bt,
                          float* __restrict__ C, short* __restrict__ Cs0,
                          short* __restrict__ Cs1, const float* __restrict__ bias,
                          float* __restrict__ stats, const float* __restrict__ colsum,
                          const float* __restrict__ bb, short* __restrict__ hbw,
                          int K, int lda, int ldc, int Ncut, int NXB, int NYB)
{
    constexpr int MF  = BM / 32;          // m-frags per wave
    constexpr int NFr = BN / 32;          // n-frags per wave
    __shared__ short smem[BM * 40 + BN * 40];
    const int bid = blockIdx.x;
    const int xcd = bid & 7, j = bid >> 3;
    const int by = xcd * (NYB >> 3) + j / NXB;
    const int bx = j - (j / NXB) * NXB;
    const int m0 = by * BM;
    const int n0 = bx * BN;

    const int tid = threadIdx.x;
    const int lane = tid & 63, w = tid >> 6;
    const int wr = w >> 1, wc = w & 1;
    const int lr = lane & 15, lk = lane >> 4;

    f32x4 acc[MF][NFr] = {};
    for (int k0 = 0; k0 < K; k0 += 32) {
        __syncthreads();
#pragma unroll
        for (int i = 0; i < BM / 64; ++i) {
            int c = tid + i * 256;
            int row = c >> 2, seg = c & 3;
            bf16x8 v = *(const bf16x8*)(A + (size_t)(m0 + row) * lda + k0 + seg * 8);
            *(bf16x8*)(&smem[row * 40 + seg * 8]) = v;
        }
#pragma unroll
        for (int i = 0; i < BN / 64; ++i) {
            int c = tid + i * 256;
            int row = c >> 2, seg = c & 3;
            bf16x8 v = *(const bf16x8*)(Bt + (size_t)(n0 + row) * K + k0 + seg * 8);
            *(bf16x8*)(&smem[BM * 40 + row * 40 + seg * 8]) = v;
        }
        __syncthreads();
        bf16x8 af[MF], bfr[NFr];
#pragma unroll
        for (int m = 0; m < MF; ++m)
            af[m] = *(const bf16x8*)(&smem[(wr * (BM / 2) + m * 16 + lr) * 40 + lk * 8]);
#pragma unroll
        for (int n = 0; n < NFr; ++n)
            bfr[n] = *(const bf16x8*)(&smem[BM * 40 + (wc * (BN / 2) + n * 16 + lr) * 40 + lk * 8]);
#pragma unroll
        for (int m = 0; m < MF; ++m)
#pragma unroll
            for (int n = 0; n < NFr; ++n)
                acc[m][n] = __builtin_amdgcn_mfma_f32_16x16x32_bf16(af[m], bfr[n], acc[m][n], 0, 0, 0);
    }
#pragma unroll
    for (int m = 0; m < MF; ++m) {
#pragma unroll
        for (int j2 = 0; j2 < 4; ++j2) {
            const int row = m0 + wr * (BM / 2) + m * 16 + lk * 4 + j2;
            float mu = 0.f, rsv = 0.f;
            if (EP == 0) {
                float s1 = stats[row * 2], s2 = stats[row * 2 + 1];
                mu = s1 * (1.f / DM);
                float var = s2 * (1.f / DM) - mu * mu;
                rsv = 1.f / sqrtf(var + 1e-5f);
            }
            float s1 = 0.f, s2 = 0.f;
#pragma unroll
            for (int n = 0; n < NFr; ++n) {
                const int col = n0 + wc * (BN / 2) + n * 16 + lr;
                float v = acc[m][n][j2];
                if (EP == 0) {
                    v = rsv * v - rsv * mu * colsum[col] + bb[col];
                    if (col < DI) Cs0[(size_t)row * DI + col] = f2bf(v);
                    else          Cs1[(size_t)row * DI + col - DI] = f2bf(siluf(v));
                } else if (EP == 1) {
                    if (col < Ncut) C[(size_t)row * ldc + col] = v;
                } else {
                    if (EP == 2) v += C[(size_t)row * ldc + col];
                    else         v += bias[col];
                    C[(size_t)row * ldc + col] = v;
                    hbw[(size_t)row * ldc + col] = f2bf(v);
                    s1 += v; s2 += v * v;
                }
            }
            if (EP == 2 || EP == 3) {
                s1 += __shfl_xor(s1, 1); s2 += __shfl_xor(s2, 1);
                s1 += __shfl_xor(s1, 2); s2 += __shfl_xor(s2, 2);
                s1 += __shfl_xor(s1, 4); s2 += __shfl_xor(s2, 4);
                s1 += __shfl_xor(s1, 8); s2 += __shfl_xor(s2, 8);
                if (lr == 0) {
                    atomicAdd(&stats[row * 2], s1);
                    atomicAdd(&stats[row * 2 + 1], s2);
                }
            }
        }
    }
}

// ---------------------------------------------------------------------------
// Depthwise causal conv (width 4) + bias + SiLU.  bf16 in/out, 4 chans/thread.
// ---------------------------------------------------------------------------
__global__ void conv_silu_kernel(const short* __restrict__ xsb,
                                 const float* __restrict__ W,   // [4, DI]
                                 const float* __restrict__ Bc,  // [DI]
                                 short* __restrict__ xcb)
{
    const int idx = blockIdx.x * 256 + threadIdx.x;   // over ROWS*DI/4
    const int c4 = idx & (DI / 4 - 1);
    const int bt = idx >> 7;
    const int t = bt & (T - 1);
    const int c = c4 * 4;
    f32x4 acc = *(const f32x4*)(Bc + c);
#pragma unroll
    for (int k = 0; k < 4; ++k) {
        int tt = t + k - 3;
        if (tt >= 0) {
            s16x4 v = *(const s16x4*)(xsb + (size_t)(bt + k - 3) * DI + c);
            f32x4 wv = *(const f32x4*)(W + k * DI + c);
#pragma unroll
            for (int q = 0; q < 4; ++q) acc[q] += bf2f(v[q]) * wv[q];
        }
    }
    s16x4 o;
#pragma unroll
    for (int q = 0; q < 4; ++q) o[q] = f2bf(siluf(acc[q]));
    *(s16x4*)(xcb + (size_t)idx * 4) = o;
}

// ---------------------------------------------------------------------------
// Chunked selective scan, lane-per-d; dt-projection fused; structured-A
// fast path (a[s] = g^(s+1)) with generic 16-exp fallback.
// ---------------------------------------------------------------------------
__global__ void scan_pass1(const float* __restrict__ xd,
                           const short* __restrict__ xcb,
                           const float* __restrict__ negA2, // [DI*DS] slice
                           const float* __restrict__ dtWt,  // [DI*DR] slice
                           const float* __restrict__ dtB,   // [DI] slice
                           float* __restrict__ S, float* __restrict__ sdtb)
{
    __shared__ float lds[CL][32];   // [t][0:16]=dt_r, [16:32]=Bm
    const int d = blockIdx.x * 256 + threadIdx.x;
    const int c = blockIdx.y;
    const int b = blockIdx.z;
    const int row0 = b * T + c * CL;

    {
        int t = threadIdx.x >> 3, seg = threadIdx.x & 7;
        *(f32x4*)&lds[t][seg * 4] =
            *(const f32x4*)(xd + (size_t)(row0 + t) * XD + seg * 4);
    }
    float A2[DS], h[DS], wcol[DR];
#pragma unroll
    for (int q = 0; q < 4; ++q) {
        *(f32x4*)&A2[q * 4]   = *(const f32x4*)(negA2 + d * DS + q * 4);
        *(f32x4*)&wcol[q * 4] = *(const f32x4*)(dtWt + d * DR + q * 4);
    }
    bool fastb = true;
#pragma unroll
    for (int s = 1; s < DS; ++s)
        fastb = fastb && (fabsf(A2[s] - A2[0] * (float)(s + 1)) <= 1e-4f * fabsf(A2[s]));
    const bool fast = __all(fastb);
#pragma unroll
    for (int s = 0; s < DS; ++s) h[s] = 0.f;
    const float dtBd = dtB[d];
    float sdt = 0.f;
    __syncthreads();

    for (int t = 0; t < CL; ++t) {
        float xcv = bf2f(xcb[(size_t)(row0 + t) * DI + d]);
        float accd = dtBd;
#pragma unroll
        for (int q = 0; q < 4; ++q) {
            f32x4 xr = *(const f32x4*)&lds[t][q * 4];
            accd += xr[0] * wcol[q * 4] + xr[1] * wcol[q * 4 + 1]
                  + xr[2] * wcol[q * 4 + 2] + xr[3] * wcol[q * 4 + 3];
        }
        float dtv = softplusf(accd);
        float dx = dtv * xcv;
        sdt += dtv;
        float a[DS];
        if (fast) powers16(fexp2(dtv * A2[0]), a);
        else {
#pragma unroll
            for (int s = 0; s < DS; ++s) a[s] = fexp2(dtv * A2[s]);
        }
#pragma unroll
        for (int q = 0; q < 4; ++q) {
            f32x4 Bv = *(const f32x4*)&lds[t][16 + q * 4];
#pragma unroll
            for (int s = 0; s < 4; ++s)
                h[q * 4 + s] = a[q * 4 + s] * h[q * 4 + s] + dx * Bv[s];
        }
    }
    const size_t base = (size_t)c * SCN + ((size_t)b * DI + d) * DS;
#pragma unroll
    for (int q = 0; q < 4; ++q)
        *(f32x4*)(S + base + q * 4) = *(f32x4*)&h[q * 4];
    sdtb[c * (NB * DI) + b * DI + d] = sdt;
}

// In-place combine: S[c] <- state entering chunk c (recomputes decay from sdt).
__global__ void scan_combine(float* __restrict__ S, const float* __restrict__ sdtb,
                             const float* __restrict__ negA2)
{
    const int idx3 = blockIdx.x * blockDim.x + threadIdx.x;  // SCN
    const int bd = idx3 >> 4;
    const float A2c = negA2[(bd & (DI - 1)) * DS + (idx3 & 15)];
    float h = 0.f;
    for (int c = 0; c < NC; ++c) {
        float sc = S[(size_t)c * SCN + idx3];
        float pc = fexp2(A2c * sdtb[c * (NB * DI) + bd]);
        S[(size_t)c * SCN + idx3] = h;
        h = pc * h + sc;
    }
}

__global__ void scan_pass2(const float* __restrict__ xd,
                           const short* __restrict__ xcb,
                           const float* __restrict__ negA2,
                           const float* __restrict__ dtWt,
                           const float* __restrict__ dtB,
                           const float* __restrict__ Dv,
                           const float* __restrict__ H,    // [NC][SCN] (=S)
                           const short* __restrict__ zgb,  // bf16 silu(z)
                           short* __restrict__ yb,         // bf16 out (gated)
                           float* __restrict__ stats)      // zeroed for out-proj
{
    __shared__ float lds[CL][48];   // [t][0:16]=dt_r, [16:32]=Bm, [32:48]=Cm
    const int d = blockIdx.x * 256 + threadIdx.x;
    const int c = blockIdx.y;
    const int b = blockIdx.z;
    const int row0 = b * T + c * CL;

    // zero the row-stats slots this (c,b) tile owns (for the following out-proj)
    if (blockIdx.x == 0 && threadIdx.x < CL * 2)
        stats[(size_t)(row0 + (threadIdx.x >> 1)) * 2 + (threadIdx.x & 1)] = 0.f;

    for (int c0 = threadIdx.x; c0 < CL * 12; c0 += 256) {
        int t = c0 / 12, seg = c0 - t * 12;
        *(f32x4*)&lds[t][seg * 4] =
            *(const f32x4*)(xd + (size_t)(row0 + t) * XD + seg * 4);
    }
    float A2[DS], h[DS], wcol[DR];
#pragma unroll
    for (int q = 0; q < 4; ++q) {
        *(f32x4*)&A2[q * 4]   = *(const f32x4*)(negA2 + d * DS + q * 4);
        *(f32x4*)&wcol[q * 4] = *(const f32x4*)(dtWt + d * DR + q * 4);
    }
    bool fastb = true;
#pragma unroll
    for (int s = 1; s < DS; ++s)
        fastb = fastb && (fabsf(A2[s] - A2[0] * (float)(s + 1)) <= 1e-4f * fabsf(A2[s]));
    const bool fast = __all(fastb);
    const size_t base = (size_t)c * SCN + ((size_t)b * DI + d) * DS;
#pragma unroll
    for (int q = 0; q < 4; ++q)
        *(f32x4*)&h[q * 4] = *(const f32x4*)(H + base + q * 4);
    const float dtBd = dtB[d];
    const float Dd = Dv[d];
    __syncthreads();

    for (int t = 0; t < CL; ++t) {
        const size_t row = (size_t)(row0 + t);
        float xcv = bf2f(xcb[row * DI + d]);
        float zg  = bf2f(zgb[row * DI + d]);
        float accd = dtBd;
#pragma unroll
        for (int q = 0; q < 4; ++q) {
            f32x4 xr = *(const f32x4*)&lds[t][q * 4];
            accd += xr[0] * wcol[q * 4] + xr[1] * wcol[q * 4 + 1]
                  + xr[2] * wcol[q * 4 + 2] + xr[3] * wcol[q * 4 + 3];
        }
        float dtv = softplusf(accd);
        float dx = dtv * xcv;
        float a[DS];
        if (fast) powers16(fexp2(dtv * A2[0]), a);
        else {
#pragma unroll
            for (int s = 0; s < DS; ++s) a[s] = fexp2(dtv * A2[s]);
        }
        float acc0 = 0.f, acc1 = 0.f, acc2 = 0.f, acc3 = 0.f;
#pragma unroll
        for (int q = 0; q < 4; ++q) {
            f32x4 Bv = *(const f32x4*)&lds[t][16 + q * 4];
            f32x4 Cv = *(const f32x4*)&lds[t][32 + q * 4];
            h[q * 4 + 0] = a[q * 4 + 0] * h[q * 4 + 0] + dx * Bv[0];
            acc0 += h[q * 4 + 0] * Cv[0];
            h[q * 4 + 1] = a[q * 4 + 1] * h[q * 4 + 1] + dx * Bv[1];
            acc1 += h[q * 4 + 1] * Cv[1];
            h[q * 4 + 2] = a[q * 4 + 2] * h[q * 4 + 2] + dx * Bv[2];
            acc2 += h[q * 4 + 2] * Cv[2];
            h[q * 4 + 3] = a[q * 4 + 3] * h[q * 4 + 3] + dx * Bv[3];
            acc3 += h[q * 4 + 3] * Cv[3];
        }
        float yv = (acc0 + acc1) + (acc2 + acc3);
        yb[row * DI + d] = f2bf((yv + xcv * Dd) * zg);
    }
}

// ---------------------------------------------------------------------------
// Head: final LN on last token, gelu(last@h1W+h1b) @ h2W + h2b.
// ---------------------------------------------------------------------------
__global__ void head_kernel(const float* __restrict__ h,
                            const float* __restrict__ fw, const float* __restrict__ fb,
                            const float* __restrict__ h1W, const float* __restrict__ h1b,
                            const float* __restrict__ h2W, const float* __restrict__ h2b,
                            float* __restrict__ out)
{
    const int bi = blockIdx.x;
    const int t = threadIdx.x;
    const int wid = t >> 6, lane = t & 63;
    __shared__ float red[4];
    __shared__ float ln[DM];
    __shared__ float hid[DM / 2];

    const float* row = h + ((bi + 1) * T - 1) * DM;
    float v = row[t];
    float s = v;
#pragma unroll
    for (int o = 32; o >= 1; o >>= 1) s += __shfl_xor(s, o);
    if (lane == 0) red[wid] = s;
    __syncthreads();
    float mu = (red[0] + red[1] + red[2] + red[3]) * (1.f / DM);
    __syncthreads();
    float d = v - mu;
    float q = d * d;
#pragma unroll
    for (int o = 32; o >= 1; o >>= 1) q += __shfl_xor(q, o);
    if (lane == 0) red[wid] = q;
    __syncthreads();
    float var = (red[0] + red[1] + red[2] + red[3]) * (1.f / DM);
    ln[t] = d * (1.f / sqrtf(var + 1e-5f)) * fw[t] + fb[t];
    __syncthreads();

    if (t < DM / 2) {
        float acc = h1b[t];
        for (int k = 0; k < DM; ++k) acc += ln[k] * h1W[k * (DM / 2) + t];
        float x3 = acc * acc * acc;
        hid[t] = 0.5f * acc * (1.f + tanhf(0.7978845608028654f * (acc + 0.044715f * x3)));
    }
    __syncthreads();
    if (t < 3) {
        float acc = h2b[t];
        for (int k = 0; k < DM / 2; ++k) acc += hid[k] * h2W[k * 3 + t];
        out[bi * 3 + t] = acc;
    }
}

} // namespace

extern "C" void kernel_launch(void* const* d_in, const int* in_sizes, int n_in,
                              void* d_out, int out_size, void* d_ws, size_t ws_size,
                              hipStream_t stream)
{
    (void)in_sizes; (void)n_in; (void)out_size; (void)ws_size;
    const float* x     = (const float*)d_in[0];
    const float* in_w  = (const float*)d_in[1];
    const float* in_b  = (const float*)d_in[2];
    const float* ln_w  = (const float*)d_in[3];
    const float* ln_b  = (const float*)d_in[4];
    const float* inW   = (const float*)d_in[5];
    const float* convW = (const float*)d_in[6];
    const float* convB = (const float*)d_in[7];
    const float* xpW   = (const float*)d_in[8];
    const float* dtW   = (const float*)d_in[9];
    const float* A_log = (const float*)d_in[10];
    const float* Dv    = (const float*)d_in[11];
    const float* outW  = (const float*)d_in[12];
    const float* fln_w = (const float*)d_in[13];
    const float* fln_b = (const float*)d_in[14];
    const float* h1W   = (const float*)d_in[15];
    const float* h1b   = (const float*)d_in[16];
    const float* h2W   = (const float*)d_in[17];
    const float* h2b   = (const float*)d_in[18];
    const float* dtB   = (const float*)d_in[19];
    float* out = (float*)d_out;

    float* w = (float*)d_ws;
    float* hbuf   = w;  w += ROWS * DM;
    float* xd     = w;  w += ROWS * XD;
    float* S      = w;  w += (size_t)SCN * NC;
    float* sdtb   = w;  w += NC * NB * DI;
    float* negA2  = w;  w += NL * DI * DS;
    float* dtWt   = w;  w += NL * DI * DR;
    float* colsum = w;  w += NL * 1024;
    float* bbv    = w;  w += NL * 1024;
    float* stats  = w;  w += ROWS * 2;
    short* hb    = (short*)w;
    short* xb    = hb   + (size_t)ROWS * DM;
    short* xsb   = xb   + (size_t)ROWS * NF;
    short* zgb   = xsb  + (size_t)ROWS * DI;
    short* xcb   = zgb  + (size_t)ROWS * DI;
    short* yb    = xcb  + (size_t)ROWS * DI;
    short* inWt  = yb   + (size_t)ROWS * DI;      // [4][1024][256] (ln_w-folded)
    short* xpWt  = inWt + (size_t)NL * 1024 * DM; // [4][64][512]
    short* outWt = xpWt + (size_t)NL * 64 * DI;   // [4][256][512]
    short* inwT  = outWt + (size_t)NL * DM * DI;  // [256][32]

    // --- all prep in one launch ---
    prep_all<<<(PTOT + 255) / 256, 256, 0, stream>>>(
        inW, xpW, outW, in_w, dtW, A_log, x, ln_w, ln_b,
        inWt, xpWt, outWt, inwT, dtWt, negA2, xb, colsum, bbv, stats);

    // h = x @ in_w + in_b  (MFMA; writes hbuf fp32 + hb bf16 + row stats)
    gemm_mfma<3, 128, 64><<<(DM / 64) * (ROWS / 128), 256, 0, stream>>>(
        xb, inwT, hbuf, nullptr, nullptr, in_b, stats, nullptr, nullptr, hb,
        NF, NF, DM, 0, DM / 64, ROWS / 128);

    for (int i = 0; i < NL; ++i) {
        // LN-fused in-proj: xz = LN(h) @ inW[i] -> bf16 xs | bf16 silu(z)
        gemm_mfma<0, 128, 128><<<(1024 / 128) * (ROWS / 128), 256, 0, stream>>>(
            hb, inWt + (size_t)i * 1024 * DM, nullptr, xsb, zgb, nullptr,
            stats, colsum + i * 1024, bbv + i * 1024, nullptr,
            DM, DM, 0, 0, 1024 / 128, ROWS / 128);

        conv_silu_kernel<<<ROWS * DI / 1024, 256, 0, stream>>>(
            xsb, convW + i * 4 * DI, convB + i * DI, xcb);

        // xd = xc @ xpW[i]   (BM=64 tile -> 256 blocks)
        gemm_mfma<1, 64, 64><<<1 * (ROWS / 64), 256, 0, stream>>>(
            xcb, xpWt + (size_t)i * 64 * DI, xd, nullptr, nullptr, nullptr,
            nullptr, nullptr, nullptr, nullptr, DI, DI, XD, XD, 1, ROWS / 64);

        scan_pass1<<<dim3(DI / 256, NC, NB), 256, 0, stream>>>(
            xd, xcb, negA2 + i * DI * DS, dtWt + i * DI * DR, dtB + i * DI, S, sdtb);
        scan_combine<<<SCN / 256, 256, 0, stream>>>(S, sdtb, negA2 + i * DI * DS);
        scan_pass2<<<dim3(DI / 256, NC, NB), 256, 0, stream>>>(
            xd, xcb, negA2 + i * DI * DS, dtWt + i * DI * DR, dtB + i * DI,
            Dv + i * DI, S, zgb, yb, stats);

        // h += y @ outW[i]; writes hbuf fp32 + hb bf16 + row stats
        gemm_mfma<2, 128, 128><<<(DM / 128) * (ROWS / 128), 256, 0, stream>>>(
            yb, outWt + (size_t)i * DM * DI, hbuf, nullptr, nullptr, nullptr,
            stats, nullptr, nullptr, hb, DI, DI, DM, 0, DM / 128, ROWS / 128);
    }

    head_kernel<<<NB, DM, 0, stream>>>(hbuf, fln_w, fln_b, h1W, h1b, h2W, h2b, out);
}